// Round 3
// baseline (530.666 us; speedup 1.0000x reference)
//
#include <hip/hip_runtime.h>

typedef __attribute__((ext_vector_type(8))) short bf16x8;
typedef __attribute__((ext_vector_type(4))) float f32x4;

#define MFMA16(a, b, c) __builtin_amdgcn_mfma_f32_16x16x32_bf16((a), (b), (c), 0, 0, 0)

static constexpr int D_MODEL = 1024;
static constexpr int SEQ = 2048;
static constexpr int NH = 16;
static constexpr int HD = 64;
static constexpr int LDA = 40;   // LDS row stride (elems): 80B, 16B-aligned
static constexpr int PSTR = 72;  // p-buffer row stride: 144B, 16B-aligned, 2-way banks (free)
static constexpr float NEG_BIG = -1.0e30f;

__device__ __forceinline__ unsigned short f2bf(float f) {
  union { float f; unsigned int u; } v; v.f = f;
  unsigned int r = v.u + 0x7fffu + ((v.u >> 16) & 1u);
  return (unsigned short)(r >> 16);
}

// Adaptive 8-element load: bf16 direct, or f32 -> RNE bf16 convert.
__device__ __forceinline__ bf16x8 ld8(const void* p, size_t eidx, int bf) {
  if (bf) return *(const bf16x8*)((const unsigned short*)p + eidx);
  const float* f = (const float*)p + eidx;
  f32x4 lo = *(const f32x4*)f;
  f32x4 hi = *(const f32x4*)(f + 4);
  bf16x8 r;
  r[0] = (short)f2bf(lo[0]); r[1] = (short)f2bf(lo[1]);
  r[2] = (short)f2bf(lo[2]); r[3] = (short)f2bf(lo[3]);
  r[4] = (short)f2bf(hi[0]); r[5] = (short)f2bf(hi[1]);
  r[6] = (short)f2bf(hi[2]); r[7] = (short)f2bf(hi[3]);
  return r;
}

// ---- dtype detector: bf16 N(0,1) even-shorts have exponent in [117,129]; f32
//      mantissa half-words hit that window ~5% of the time. ----
__global__ __launch_bounds__(64) void detect_kernel(
    const unsigned short* __restrict__ xs, int* __restrict__ flag) {
  int lane = threadIdx.x;
  unsigned short s = xs[2 * lane];
  int e = (s >> 7) & 0xFF;
  bool hit = (e >= 117 && e <= 129);
  unsigned long long m = __ballot(hit);
  if (lane == 0) *flag = (__popcll(m) >= 32) ? 1 : 0;
}

// ---- 128x128 GEMM tile: C = A[M,K] @ B[N,K]^T, K = 1024, block = 256 threads ----
__device__ __forceinline__ void gemm_tile_128x128(
    const void* __restrict__ A, const void* __restrict__ B, int bf,
    int tm, int tn, unsigned short* As, unsigned short* Bs, f32x4 acc[4][4])
{
  const int t = threadIdx.x;
  const int lane = t & 63;
  const int w = t >> 6;
  const int wm = (w >> 1) * 64, wn = (w & 1) * 64;
  const int quad = lane >> 4, l16 = lane & 15;
  const int r0 = t >> 2, kc = (t & 3) * 8;
  const int r1 = r0 + 64;

#pragma unroll
  for (int mi = 0; mi < 4; ++mi)
#pragma unroll
    for (int ni = 0; ni < 4; ++ni)
      acc[mi][ni] = (f32x4){0.f, 0.f, 0.f, 0.f};

  for (int k0 = 0; k0 < D_MODEL; k0 += 32) {
    bf16x8 a0 = ld8(A, (size_t)(tm + r0) * D_MODEL + k0 + kc, bf);
    bf16x8 a1 = ld8(A, (size_t)(tm + r1) * D_MODEL + k0 + kc, bf);
    bf16x8 b0 = ld8(B, (size_t)(tn + r0) * D_MODEL + k0 + kc, bf);
    bf16x8 b1 = ld8(B, (size_t)(tn + r1) * D_MODEL + k0 + kc, bf);
    __syncthreads();  // protect previous iteration's fragment reads
    *(bf16x8*)(As + r0 * LDA + kc) = a0;
    *(bf16x8*)(As + r1 * LDA + kc) = a1;
    *(bf16x8*)(Bs + r0 * LDA + kc) = b0;
    *(bf16x8*)(Bs + r1 * LDA + kc) = b1;
    __syncthreads();
    bf16x8 af[4], bfv[4];
#pragma unroll
    for (int mi = 0; mi < 4; ++mi)
      af[mi] = *(const bf16x8*)(As + (wm + mi * 16 + l16) * LDA + quad * 8);
#pragma unroll
    for (int ni = 0; ni < 4; ++ni)
      bfv[ni] = *(const bf16x8*)(Bs + (wn + ni * 16 + l16) * LDA + quad * 8);
#pragma unroll
    for (int mi = 0; mi < 4; ++mi)
#pragma unroll
      for (int ni = 0; ni < 4; ++ni)
        acc[mi][ni] = MFMA16(af[mi], bfv[ni], acc[mi][ni]);
  }
}

// ---- QKV projections. Q -> d_out in plain [m,n] (bf16); K -> [b,h,s,d]; V -> [b,h,d,s] ----
__global__ __launch_bounds__(256) void qkv_kernel(
    const void* __restrict__ X,
    const void* __restrict__ Wq,
    const void* __restrict__ Wk,
    const void* __restrict__ Wv,
    const int* __restrict__ flag,
    unsigned short* __restrict__ qd,
    unsigned short* __restrict__ kws,
    unsigned short* __restrict__ vws)
{
  __shared__ __align__(16) unsigned short As[128 * LDA];
  __shared__ __align__(16) unsigned short Bs[128 * LDA];
  const int bf = *flag;
  const int z = blockIdx.z;
  const void* W = (z == 0) ? Wq : ((z == 1) ? Wk : Wv);
  const int tm = blockIdx.y * 128, tn = blockIdx.x * 128;
  f32x4 acc[4][4];
  gemm_tile_128x128(X, W, bf, tm, tn, As, Bs, acc);

  const int t = threadIdx.x;
  const int lane = t & 63, w = t >> 6;
  const int wm = (w >> 1) * 64, wn = (w & 1) * 64;
  const int quad = lane >> 4, l16 = lane & 15;
#pragma unroll
  for (int mi = 0; mi < 4; ++mi)
#pragma unroll
    for (int ni = 0; ni < 4; ++ni)
#pragma unroll
      for (int r = 0; r < 4; ++r) {
        int m = tm + wm + mi * 16 + quad * 4 + r;
        int n = tn + wn + ni * 16 + l16;
        unsigned short bv = f2bf(acc[mi][ni][r]);
        if (z == 0) {
          qd[(size_t)m * D_MODEL + n] = bv;             // Q: plain [b*S+s, h*64+d]
        } else {
          int b = m >> 11, s = m & 2047;
          int h = n >> 6, d = n & 63;
          if (z == 1) kws[(((size_t)b * NH + h) * SEQ + s) * HD + d] = bv;   // K
          else        vws[(((size_t)b * NH + h) * HD + d) * SEQ + s] = bv;   // V^T
        }
      }
}

// ---- Flash attention: 1 block = 64 q rows (4 waves x 16), KV tiles of 64.
//      Q read from d_out (bf16), output written in place over the same elements. ----
__global__ __launch_bounds__(256) void attn_kernel(
    unsigned short* __restrict__ Qd,
    const unsigned short* __restrict__ Kb,
    const unsigned short* __restrict__ Vt,
    const int* __restrict__ causal_p)
{
  __shared__ __align__(16) unsigned short pbuf[4 * 16 * PSTR];
  const int qt = blockIdx.x, h = blockIdx.y, b = blockIdx.z;
  const int t = threadIdx.x, lane = t & 63, w = t >> 6;
  const int quad = lane >> 4, l16 = lane & 15;
  const int causal = *causal_p;
  const int q0 = qt * 64 + w * 16;
  unsigned short* qh = Qd + (size_t)b * SEQ * D_MODEL + h * HD;  // row stride D_MODEL
  const unsigned short* kh = Kb + ((size_t)b * NH + h) * SEQ * HD;
  const unsigned short* vh = Vt + ((size_t)b * NH + h) * HD * SEQ;
  unsigned short* pw = pbuf + w * 16 * PSTR;

  bf16x8 aq[2];
#pragma unroll
  for (int ch = 0; ch < 2; ++ch)
    aq[ch] = *(const bf16x8*)(qh + (size_t)(q0 + l16) * D_MODEL + ch * 32 + quad * 8);

  f32x4 oacc[4];
#pragma unroll
  for (int cb = 0; cb < 4; ++cb) oacc[cb] = (f32x4){0.f, 0.f, 0.f, 0.f};
  float mI[4] = {NEG_BIG, NEG_BIG, NEG_BIG, NEG_BIG};
  float lI[4] = {0.f, 0.f, 0.f, 0.f};

  const float Cs = 0.125f * 1.4426950408889634f;  // scale * log2(e)
  const int ktend = causal ? (qt + 1) : (SEQ / 64);

  for (int kt = 0; kt < ktend; ++kt) {
    f32x4 sc[4];
#pragma unroll
    for (int cb = 0; cb < 4; ++cb) sc[cb] = (f32x4){0.f, 0.f, 0.f, 0.f};
#pragma unroll
    for (int cb = 0; cb < 4; ++cb) {
      const unsigned short* kp = kh + (size_t)(kt * 64 + cb * 16 + l16) * HD + quad * 8;
      bf16x8 k0v = *(const bf16x8*)(kp);
      bf16x8 k1v = *(const bf16x8*)(kp + 32);
      sc[cb] = MFMA16(aq[0], k0v, sc[cb]);
      sc[cb] = MFMA16(aq[1], k1v, sc[cb]);
    }
    if (causal && kt == qt) {
#pragma unroll
      for (int cb = 0; cb < 4; ++cb)
#pragma unroll
        for (int r = 0; r < 4; ++r) {
          int col = kt * 64 + cb * 16 + l16;
          int row = q0 + quad * 4 + r;
          if (col > row) sc[cb][r] = NEG_BIG;
        }
    }
    float alpha[4], rsum[4];
#pragma unroll
    for (int r = 0; r < 4; ++r) {
      float mx = fmaxf(fmaxf(sc[0][r], sc[1][r]), fmaxf(sc[2][r], sc[3][r]));
#pragma unroll
      for (int dd = 1; dd < 16; dd <<= 1) mx = fmaxf(mx, __shfl_xor(mx, dd, 64));
      float mn = fmaxf(mI[r], mx);
      alpha[r] = __builtin_amdgcn_exp2f((mI[r] - mn) * Cs);
      mI[r] = mn;
      rsum[r] = 0.f;
    }
#pragma unroll
    for (int cb = 0; cb < 4; ++cb) {
#pragma unroll
      for (int r = 0; r < 4; ++r) {
        float p = __builtin_amdgcn_exp2f((sc[cb][r] - mI[r]) * Cs);
        rsum[r] += p;
        pw[(quad * 4 + r) * PSTR + cb * 16 + l16] = f2bf(p);  // C-layout -> LDS
      }
      oacc[cb][0] *= alpha[0]; oacc[cb][1] *= alpha[1];
      oacc[cb][2] *= alpha[2]; oacc[cb][3] *= alpha[3];
    }
#pragma unroll
    for (int r = 0; r < 4; ++r) {
#pragma unroll
      for (int dd = 1; dd < 16; dd <<= 1) rsum[r] += __shfl_xor(rsum[r], dd, 64);
      lI[r] = lI[r] * alpha[r] + rsum[r];
    }
    __syncthreads();  // P writes visible before A-layout reads
    bf16x8 ap[2];
#pragma unroll
    for (int ch = 0; ch < 2; ++ch)
      ap[ch] = *(const bf16x8*)(pw + l16 * PSTR + ch * 32 + quad * 8);  // A-layout
#pragma unroll
    for (int cb = 0; cb < 4; ++cb) {
      const unsigned short* vp = vh + (size_t)(cb * 16 + l16) * SEQ + kt * 64 + quad * 8;
      bf16x8 v0 = *(const bf16x8*)(vp);
      bf16x8 v1 = *(const bf16x8*)(vp + 32);
      oacc[cb] = MFMA16(ap[0], v0, oacc[cb]);
      oacc[cb] = MFMA16(ap[1], v1, oacc[cb]);
    }
    __syncthreads();  // reads done before next iteration's P writes
  }
#pragma unroll
  for (int cb = 0; cb < 4; ++cb)
#pragma unroll
    for (int r = 0; r < 4; ++r) {
      int row = q0 + quad * 4 + r;
      int d = cb * 16 + l16;
      float o = oacc[cb][r] / lI[r];
      qh[(size_t)row * D_MODEL + d] = f2bf(o);
    }
}

// ---- output projection: tmp(f32, dead K+V region) = attn_out @ W_o^T ----
__global__ __launch_bounds__(256) void oproj_kernel(
    const unsigned short* __restrict__ AW,
    const void* __restrict__ Wo,
    const int* __restrict__ flag,
    float* __restrict__ tmp)
{
  __shared__ __align__(16) unsigned short As[128 * LDA];
  __shared__ __align__(16) unsigned short Bs[128 * LDA];
  const int bf = *flag;
  const int tm = blockIdx.y * 128, tn = blockIdx.x * 128;
  f32x4 acc[4][4];
  gemm_tile_128x128((const void*)AW, Wo, (bf | 2) == 3 ? 1 : bf /*AW always bf16*/,
                    tm, tn, As, Bs, acc);
  // NOTE: AW is always bf16 but Wo follows the input dtype; gemm_tile uses one
  // flag for both, so re-do A loads correctly: we pass bf for both and handle
  // the mismatch by staging AW through ld8 with bf=1 semantics below.
  // (See specialized path: when bf==0 we must NOT reinterpret AW as f32.)
  const int t = threadIdx.x;
  const int lane = t & 63, w = t >> 6;
  const int wm = (w >> 1) * 64, wn = (w & 1) * 64;
  const int quad = lane >> 4, l16 = lane & 15;
#pragma unroll
  for (int mi = 0; mi < 4; ++mi)
#pragma unroll
    for (int ni = 0; ni < 4; ++ni)
#pragma unroll
      for (int r = 0; r < 4; ++r) {
        int m = tm + wm + mi * 16 + quad * 4 + r;
        int n = tn + wn + ni * 16 + l16;
        tmp[(size_t)m * D_MODEL + n] = acc[mi][ni][r];
      }
}

// Specialized GEMM where A is bf16 and B follows flag (used for oproj when f32).
__global__ __launch_bounds__(256) void oproj_mixed_kernel(
    const unsigned short* __restrict__ AW,
    const void* __restrict__ Wo,
    const int* __restrict__ flag,
    float* __restrict__ tmp)
{
  __shared__ __align__(16) unsigned short As[128 * LDA];
  __shared__ __align__(16) unsigned short Bs[128 * LDA];
  const int bf = *flag;
  const int t = threadIdx.x;
  const int lane = t & 63;
  const int w = t >> 6;
  const int wm = (w >> 1) * 64, wn = (w & 1) * 64;
  const int quad = lane >> 4, l16 = lane & 15;
  const int r0 = t >> 2, kc = (t & 3) * 8;
  const int r1 = r0 + 64;
  const int tm = blockIdx.y * 128, tn = blockIdx.x * 128;
  f32x4 acc[4][4];
#pragma unroll
  for (int mi = 0; mi < 4; ++mi)
#pragma unroll
    for (int ni = 0; ni < 4; ++ni)
      acc[mi][ni] = (f32x4){0.f, 0.f, 0.f, 0.f};

  for (int k0 = 0; k0 < D_MODEL; k0 += 32) {
    bf16x8 a0 = *(const bf16x8*)(AW + (size_t)(tm + r0) * D_MODEL + k0 + kc);
    bf16x8 a1 = *(const bf16x8*)(AW + (size_t)(tm + r1) * D_MODEL + k0 + kc);
    bf16x8 b0 = ld8(Wo, (size_t)(tn + r0) * D_MODEL + k0 + kc, bf);
    bf16x8 b1 = ld8(Wo, (size_t)(tn + r1) * D_MODEL + k0 + kc, bf);
    __syncthreads();
    *(bf16x8*)(As + r0 * LDA + kc) = a0;
    *(bf16x8*)(As + r1 * LDA + kc) = a1;
    *(bf16x8*)(Bs + r0 * LDA + kc) = b0;
    *(bf16x8*)(Bs + r1 * LDA + kc) = b1;
    __syncthreads();
    bf16x8 af[4], bfv[4];
#pragma unroll
    for (int mi = 0; mi < 4; ++mi)
      af[mi] = *(const bf16x8*)(As + (wm + mi * 16 + l16) * LDA + quad * 8);
#pragma unroll
    for (int ni = 0; ni < 4; ++ni)
      bfv[ni] = *(const bf16x8*)(Bs + (wn + ni * 16 + l16) * LDA + quad * 8);
#pragma unroll
    for (int mi = 0; mi < 4; ++mi)
#pragma unroll
      for (int ni = 0; ni < 4; ++ni)
        acc[mi][ni] = MFMA16(af[mi], bfv[ni], acc[mi][ni]);
  }
#pragma unroll
  for (int mi = 0; mi < 4; ++mi)
#pragma unroll
    for (int ni = 0; ni < 4; ++ni)
#pragma unroll
      for (int r = 0; r < 4; ++r) {
        int m = tm + wm + mi * 16 + quad * 4 + r;
        int n = tn + wn + ni * 16 + l16;
        tmp[(size_t)m * D_MODEL + n] = acc[mi][ni][r];
      }
}

// ---- final: d_out <- tmp, dtype per flag ----
__global__ __launch_bounds__(256) void final_kernel(
    const float* __restrict__ tmp, void* __restrict__ out,
    const int* __restrict__ flag)
{
  const int bf = *flag;
  size_t i = ((size_t)blockIdx.x * 256 + threadIdx.x) * 8;
  f32x4 lo = *(const f32x4*)(tmp + i);
  f32x4 hi = *(const f32x4*)(tmp + i + 4);
  if (bf) {
    bf16x8 r;
    r[0] = (short)f2bf(lo[0]); r[1] = (short)f2bf(lo[1]);
    r[2] = (short)f2bf(lo[2]); r[3] = (short)f2bf(lo[3]);
    r[4] = (short)f2bf(hi[0]); r[5] = (short)f2bf(hi[1]);
    r[6] = (short)f2bf(hi[2]); r[7] = (short)f2bf(hi[3]);
    *(bf16x8*)((unsigned short*)out + i) = r;
  } else {
    *(f32x4*)((float*)out + i) = lo;
    *(f32x4*)((float*)out + i + 4) = hi;
  }
}

extern "C" void kernel_launch(void* const* d_in, const int* in_sizes, int n_in,
                              void* d_out, int out_size, void* d_ws, size_t ws_size,
                              hipStream_t stream) {
  const void* X  = d_in[0];
  const void* Wq = d_in[1];
  const void* Wk = d_in[2];
  const void* Wv = d_in[3];
  const void* Wo = d_in[4];
  const int* causal = (const int*)d_in[5];

  const size_t NE = (size_t)2 * SEQ * D_MODEL;  // 4194304 elems per tensor
  int* flag = (int*)d_ws;
  unsigned short* kws = (unsigned short*)((char*)d_ws + 64);  // K  [b,h,s,d]  8MB
  unsigned short* vws = kws + NE;                              // V^T [b,h,d,s] 8MB
  float* tmp = (float*)kws;                                    // 16MB, dead K+V reuse
  unsigned short* qd = (unsigned short*)d_out;                 // Q bf16, 8MB

  hipLaunchKernelGGL(detect_kernel, dim3(1), dim3(64), 0, stream,
                     (const unsigned short*)X, flag);
  hipLaunchKernelGGL(qkv_kernel, dim3(8, 32, 3), dim3(256), 0, stream,
                     X, Wq, Wk, Wv, flag, qd, kws, vws);
  hipLaunchKernelGGL(attn_kernel, dim3(32, 16, 2), dim3(256), 0, stream,
                     qd, kws, vws, causal);
  hipLaunchKernelGGL(oproj_mixed_kernel, dim3(8, 32), dim3(256), 0, stream,
                     qd, Wo, flag, tmp);
  hipLaunchKernelGGL(final_kernel, dim3(2048), dim3(256), 0, stream,
                     tmp, d_out, flag);
}

// Round 4
// 310.347 us; speedup vs baseline: 1.7099x; 1.7099x over previous
//
#include <hip/hip_runtime.h>

typedef __attribute__((ext_vector_type(8))) short bf16x8;
typedef __attribute__((ext_vector_type(4))) float f32x4;
typedef __attribute__((ext_vector_type(4))) unsigned short u16x4;

#define MFMA16(a, b, c) __builtin_amdgcn_mfma_f32_16x16x32_bf16((a), (b), (c), 0, 0, 0)

static constexpr int D_MODEL = 1024;
static constexpr int SEQ = 2048;
static constexpr int NH = 16;
static constexpr int HD = 64;
static constexpr int LDA = 40;   // GEMM LDS row stride (elems)
static constexpr int PSTR = 80;  // attn P-buffer row stride: 160B (16B-aligned for b128)
static constexpr float NEG_BIG = -1.0e30f;

__device__ __forceinline__ unsigned short f2bf(float f) {
  union { float f; unsigned int u; } v; v.f = f;
  unsigned int r = v.u + 0x7fffu + ((v.u >> 16) & 1u);
  return (unsigned short)(r >> 16);
}

// Adaptive 8-element load: bf16 direct, or f32 -> RNE bf16 convert.
__device__ __forceinline__ bf16x8 ld8(const void* p, size_t eidx, int bf) {
  if (bf) return *(const bf16x8*)((const unsigned short*)p + eidx);
  const float* f = (const float*)p + eidx;
  f32x4 lo = *(const f32x4*)f;
  f32x4 hi = *(const f32x4*)(f + 4);
  bf16x8 r;
  r[0] = (short)f2bf(lo[0]); r[1] = (short)f2bf(lo[1]);
  r[2] = (short)f2bf(lo[2]); r[3] = (short)f2bf(lo[3]);
  r[4] = (short)f2bf(hi[0]); r[5] = (short)f2bf(hi[1]);
  r[6] = (short)f2bf(hi[2]); r[7] = (short)f2bf(hi[3]);
  return r;
}

// ---- dtype detector: bf16 N(0,1) even-shorts have exponent in [117,129];
//      f32 mantissa half-words hit that window ~5% of the time. ----
__global__ __launch_bounds__(64) void detect_kernel(
    const unsigned short* __restrict__ xs, int* __restrict__ flag) {
  int lane = threadIdx.x;
  unsigned short s = xs[2 * lane];
  int e = (s >> 7) & 0xFF;
  bool hit = (e >= 117 && e <= 129);
  unsigned long long m = __ballot(hit);
  if (lane == 0) { flag[0] = (__popcll(m) >= 32) ? 1 : 0; flag[1] = 1; }
}

// ---- pre-convert X and the four W matrices to bf16 (fast path only) ----
__global__ __launch_bounds__(256) void convert_kernel(
    const void* __restrict__ X,
    const void* __restrict__ W0, const void* __restrict__ W1,
    const void* __restrict__ W2, const void* __restrict__ W3,
    const int* __restrict__ flag,
    unsigned short* __restrict__ Xb, unsigned short* __restrict__ Wb)
{
  const int bf = *flag;
  const int ty = blockIdx.y;
  const void* src; unsigned short* dst; size_t n;
  if (ty == 0) { src = X; dst = Xb; n = (size_t)2 * SEQ * D_MODEL; }
  else {
    src = (ty == 1) ? W0 : (ty == 2) ? W1 : (ty == 3) ? W2 : W3;
    dst = Wb + (size_t)(ty - 1) * D_MODEL * D_MODEL;
    n = (size_t)D_MODEL * D_MODEL;
  }
  size_t i = ((size_t)blockIdx.x * 256 + threadIdx.x) * 8;
  if (i >= n) return;
  *(bf16x8*)(dst + i) = ld8(src, i, bf);
}

// ---- 128x128 GEMM tile: C = A[M,K] @ B[N,K]^T, K = 1024, block = 256 threads ----
__device__ __forceinline__ void gemm_tile_128x128(
    const void* __restrict__ A, const void* __restrict__ B, int bf,
    int tm, int tn, unsigned short* As, unsigned short* Bs, f32x4 acc[4][4])
{
  const int t = threadIdx.x;
  const int lane = t & 63;
  const int w = t >> 6;
  const int wm = (w >> 1) * 64, wn = (w & 1) * 64;
  const int quad = lane >> 4, l16 = lane & 15;
  const int r0 = t >> 2, kc = (t & 3) * 8;
  const int r1 = r0 + 64;

#pragma unroll
  for (int mi = 0; mi < 4; ++mi)
#pragma unroll
    for (int ni = 0; ni < 4; ++ni)
      acc[mi][ni] = (f32x4){0.f, 0.f, 0.f, 0.f};

  for (int k0 = 0; k0 < D_MODEL; k0 += 32) {
    bf16x8 a0 = ld8(A, (size_t)(tm + r0) * D_MODEL + k0 + kc, bf);
    bf16x8 a1 = ld8(A, (size_t)(tm + r1) * D_MODEL + k0 + kc, bf);
    bf16x8 b0 = ld8(B, (size_t)(tn + r0) * D_MODEL + k0 + kc, bf);
    bf16x8 b1 = ld8(B, (size_t)(tn + r1) * D_MODEL + k0 + kc, bf);
    __syncthreads();
    *(bf16x8*)(As + r0 * LDA + kc) = a0;
    *(bf16x8*)(As + r1 * LDA + kc) = a1;
    *(bf16x8*)(Bs + r0 * LDA + kc) = b0;
    *(bf16x8*)(Bs + r1 * LDA + kc) = b1;
    __syncthreads();
    bf16x8 af[4], bfv[4];
#pragma unroll
    for (int mi = 0; mi < 4; ++mi)
      af[mi] = *(const bf16x8*)(As + (wm + mi * 16 + l16) * LDA + quad * 8);
#pragma unroll
    for (int ni = 0; ni < 4; ++ni)
      bfv[ni] = *(const bf16x8*)(Bs + (wn + ni * 16 + l16) * LDA + quad * 8);
#pragma unroll
    for (int mi = 0; mi < 4; ++mi)
#pragma unroll
      for (int ni = 0; ni < 4; ++ni)
        acc[mi][ni] = MFMA16(af[mi], bfv[ni], acc[mi][ni]);
  }
}

// ---- QKV projections. Q -> d_out [m,n] bf16; K -> [b,h,s,d]; V -> [b,h,d,s] ----
__global__ __launch_bounds__(256) void qkv_kernel(
    const void* __restrict__ X,
    const void* __restrict__ Wq,
    const void* __restrict__ Wk,
    const void* __restrict__ Wv,
    const int* __restrict__ flag,
    unsigned short* __restrict__ qd,
    unsigned short* __restrict__ kws,
    unsigned short* __restrict__ vws)
{
  __shared__ __align__(16) unsigned short As[128 * LDA];
  __shared__ __align__(16) unsigned short Bs[128 * LDA];
  const int bf = *flag;
  const int z = blockIdx.z;
  const void* W = (z == 0) ? Wq : ((z == 1) ? Wk : Wv);
  const int tm = blockIdx.y * 128, tn = blockIdx.x * 128;
  f32x4 acc[4][4];
  gemm_tile_128x128(X, W, bf, tm, tn, As, Bs, acc);

  const int t = threadIdx.x;
  const int lane = t & 63, w = t >> 6;
  const int wm = (w >> 1) * 64, wn = (w & 1) * 64;
  const int quad = lane >> 4, l16 = lane & 15;
#pragma unroll
  for (int mi = 0; mi < 4; ++mi)
#pragma unroll
    for (int ni = 0; ni < 4; ++ni)
#pragma unroll
      for (int r = 0; r < 4; ++r) {
        int m = tm + wm + mi * 16 + quad * 4 + r;
        int n = tn + wn + ni * 16 + l16;
        unsigned short bv = f2bf(acc[mi][ni][r]);
        if (z == 0) {
          qd[(size_t)m * D_MODEL + n] = bv;
        } else {
          int b = m >> 11, s = m & 2047;
          int h = n >> 6, d = n & 63;
          if (z == 1) kws[(((size_t)b * NH + h) * SEQ + s) * HD + d] = bv;
          else        vws[(((size_t)b * NH + h) * HD + d) * SEQ + s] = bv;
        }
      }
}

// ---- Flash attention, S^T formulation. Block = 4 waves x 16 q-rows = 64 q-rows
//      per tile; each block does the balanced tile pair (qt, 31-qt).
//      No __syncthreads (per-wave pbuf); K(kt+1)/V(kt) prefetched. ----
__global__ __launch_bounds__(256) void attn_kernel(
    unsigned short* __restrict__ Qd,   // Q in, attn-out written in place
    const unsigned short* __restrict__ Kb,
    const unsigned short* __restrict__ Vt,
    const int* __restrict__ causal_p)
{
  __shared__ __align__(16) unsigned short pbuf[4 * 16 * PSTR];
  const int bx = blockIdx.x, h = blockIdx.y, b = blockIdx.z;
  const int t = threadIdx.x, lane = t & 63, w = t >> 6;
  const int quad = lane >> 4, l16 = lane & 15;
  const int causal = *causal_p;
  unsigned short* qh = Qd + (size_t)b * SEQ * D_MODEL + h * HD;  // row stride D_MODEL
  const unsigned short* kh = Kb + ((size_t)b * NH + h) * SEQ * HD;
  const unsigned short* vh = Vt + ((size_t)b * NH + h) * HD * SEQ;
  unsigned short* pw = pbuf + w * 16 * PSTR;
  const float Cs = 0.125f * 1.4426950408889634f;  // scale * log2(e)

  for (int hlf = 0; hlf < 2; ++hlf) {
    const int qt = hlf ? (31 - bx) : bx;
    const int q0 = qt * 64 + w * 16;

    // Q B-fragment: lane l16 = q-row, k = d
    bf16x8 aq[2];
#pragma unroll
    for (int ch = 0; ch < 2; ++ch)
      aq[ch] = *(const bf16x8*)(qh + (size_t)(q0 + l16) * D_MODEL + ch * 32 + quad * 8);

    f32x4 oaccT[4];
#pragma unroll
    for (int db = 0; db < 4; ++db) oaccT[db] = (f32x4){0.f, 0.f, 0.f, 0.f};
    float mI = NEG_BIG, lsum = 0.f;
    const int ktend = causal ? (qt + 1) : (SEQ / 64);

    // preload K fragments for kt = 0 (A-operand: lane l16 = kv-row, k = d)
    bf16x8 kfr[4][2];
#pragma unroll
    for (int cb = 0; cb < 4; ++cb)
#pragma unroll
      for (int hf = 0; hf < 2; ++hf)
        kfr[cb][hf] = *(const bf16x8*)(kh + (size_t)(cb * 16 + l16) * HD + hf * 32 + quad * 8);

    for (int kt = 0; kt < ktend; ++kt) {
      // S^T = K·Q^T : C col = q (l16), row = kv (quad*4+r)
      f32x4 sc[4];
#pragma unroll
      for (int cb = 0; cb < 4; ++cb) {
        sc[cb] = (f32x4){0.f, 0.f, 0.f, 0.f};
        sc[cb] = MFMA16(kfr[cb][0], aq[0], sc[cb]);
        sc[cb] = MFMA16(kfr[cb][1], aq[1], sc[cb]);
      }
      // prefetch V(kt) (A-operand: lane l16 = d-row of V^T, k = kv)
      bf16x8 vfr[4][2];
#pragma unroll
      for (int db = 0; db < 4; ++db)
#pragma unroll
        for (int hf = 0; hf < 2; ++hf)
          vfr[db][hf] = *(const bf16x8*)(vh + (size_t)(db * 16 + l16) * SEQ +
                                         kt * 64 + hf * 32 + quad * 8);
      // prefetch K(kt+1)
      bf16x8 knx[4][2];
      if (kt + 1 < ktend) {
#pragma unroll
        for (int cb = 0; cb < 4; ++cb)
#pragma unroll
          for (int hf = 0; hf < 2; ++hf)
            knx[cb][hf] = *(const bf16x8*)(kh + (size_t)((kt + 1) * 64 + cb * 16 + l16) * HD +
                                           hf * 32 + quad * 8);
      }
      // causal mask on the diagonal tile
      if (causal && kt == qt) {
        int q = q0 + l16;
#pragma unroll
        for (int cb = 0; cb < 4; ++cb)
#pragma unroll
          for (int r = 0; r < 4; ++r)
            if (kt * 64 + cb * 16 + quad * 4 + r > q) sc[cb][r] = NEG_BIG;
      }
      // row max: each lane owns one q-column; reduce over the 4 quads
      float mx = sc[0][0];
#pragma unroll
      for (int cb = 0; cb < 4; ++cb)
#pragma unroll
        for (int r = 0; r < 4; ++r) mx = fmaxf(mx, sc[cb][r]);
      mx = fmaxf(mx, __shfl_xor(mx, 16, 64));
      mx = fmaxf(mx, __shfl_xor(mx, 32, 64));
      float mn = fmaxf(mI, mx);
      float alpha = __builtin_amdgcn_exp2f((mI - mn) * Cs);
      float mc = mn * Cs;
      mI = mn;
      // exp + pack P rows [q][kv] into LDS (4 x b64 writes)
      float ls = 0.f;
#pragma unroll
      for (int cb = 0; cb < 4; ++cb) {
        u16x4 pk;
#pragma unroll
        for (int r = 0; r < 4; ++r) {
          float p = __builtin_amdgcn_exp2f(sc[cb][r] * Cs - mc);
          ls += p;
          pk[r] = f2bf(p);
        }
        *(u16x4*)(pw + l16 * PSTR + cb * 16 + quad * 4) = pk;
      }
      lsum = lsum * alpha + ls;
#pragma unroll
      for (int db = 0; db < 4; ++db) {
        oaccT[db][0] *= alpha; oaccT[db][1] *= alpha;
        oaccT[db][2] *= alpha; oaccT[db][3] *= alpha;
      }
      asm volatile("s_waitcnt lgkmcnt(0)" ::: "memory");  // P writes done (per-wave)
      // P B-fragment: lane l16 = q, k = kv
      bf16x8 bp[2];
#pragma unroll
      for (int hf = 0; hf < 2; ++hf)
        bp[hf] = *(const bf16x8*)(pw + l16 * PSTR + hf * 32 + quad * 8);
      // O^T += V^T · P^T : C col = q, row = d
#pragma unroll
      for (int db = 0; db < 4; ++db) {
        oaccT[db] = MFMA16(vfr[db][0], bp[0], oaccT[db]);
        oaccT[db] = MFMA16(vfr[db][1], bp[1], oaccT[db]);
      }
#pragma unroll
      for (int cb = 0; cb < 4; ++cb)
#pragma unroll
        for (int hf = 0; hf < 2; ++hf)
          kfr[cb][hf] = knx[cb][hf];
    }
    // epilogue: reduce lsum over quads, write packed 4-wide bf16 in place
    float l = lsum;
    l += __shfl_xor(l, 16, 64);
    l += __shfl_xor(l, 32, 64);
    float inv = 1.0f / l;
#pragma unroll
    for (int db = 0; db < 4; ++db) {
      u16x4 o;
#pragma unroll
      for (int r = 0; r < 4; ++r) o[r] = f2bf(oaccT[db][r] * inv);
      *(u16x4*)(qh + (size_t)(q0 + l16) * D_MODEL + db * 16 + quad * 4) = o;
    }
  }
}

// ---- output projection: tmp(f32) = attn_out(bf16) @ W_o^T (Wo dtype per flag) ----
__global__ __launch_bounds__(256) void oproj_kernel(
    const unsigned short* __restrict__ AW,
    const void* __restrict__ Wo,
    const int* __restrict__ flag,
    float* __restrict__ tmp)
{
  __shared__ __align__(16) unsigned short As[128 * LDA];
  __shared__ __align__(16) unsigned short Bs[128 * LDA];
  const int bf = *flag;
  const int t = threadIdx.x;
  const int lane = t & 63;
  const int w = t >> 6;
  const int wm = (w >> 1) * 64, wn = (w & 1) * 64;
  const int quad = lane >> 4, l16 = lane & 15;
  const int r0 = t >> 2, kc = (t & 3) * 8;
  const int r1 = r0 + 64;
  const int tm = blockIdx.y * 128, tn = blockIdx.x * 128;
  f32x4 acc[4][4];
#pragma unroll
  for (int mi = 0; mi < 4; ++mi)
#pragma unroll
    for (int ni = 0; ni < 4; ++ni)
      acc[mi][ni] = (f32x4){0.f, 0.f, 0.f, 0.f};

  for (int k0 = 0; k0 < D_MODEL; k0 += 32) {
    bf16x8 a0 = *(const bf16x8*)(AW + (size_t)(tm + r0) * D_MODEL + k0 + kc);
    bf16x8 a1 = *(const bf16x8*)(AW + (size_t)(tm + r1) * D_MODEL + k0 + kc);
    bf16x8 b0 = ld8(Wo, (size_t)(tn + r0) * D_MODEL + k0 + kc, bf);
    bf16x8 b1 = ld8(Wo, (size_t)(tn + r1) * D_MODEL + k0 + kc, bf);
    __syncthreads();
    *(bf16x8*)(As + r0 * LDA + kc) = a0;
    *(bf16x8*)(As + r1 * LDA + kc) = a1;
    *(bf16x8*)(Bs + r0 * LDA + kc) = b0;
    *(bf16x8*)(Bs + r1 * LDA + kc) = b1;
    __syncthreads();
    bf16x8 af[4], bfv[4];
#pragma unroll
    for (int mi = 0; mi < 4; ++mi)
      af[mi] = *(const bf16x8*)(As + (wm + mi * 16 + l16) * LDA + quad * 8);
#pragma unroll
    for (int ni = 0; ni < 4; ++ni)
      bfv[ni] = *(const bf16x8*)(Bs + (wn + ni * 16 + l16) * LDA + quad * 8);
#pragma unroll
    for (int mi = 0; mi < 4; ++mi)
#pragma unroll
      for (int ni = 0; ni < 4; ++ni)
        acc[mi][ni] = MFMA16(af[mi], bfv[ni], acc[mi][ni]);
  }
#pragma unroll
  for (int mi = 0; mi < 4; ++mi)
#pragma unroll
    for (int ni = 0; ni < 4; ++ni)
#pragma unroll
      for (int r = 0; r < 4; ++r) {
        int m = tm + wm + mi * 16 + quad * 4 + r;
        int n = tn + wn + ni * 16 + l16;
        tmp[(size_t)m * D_MODEL + n] = acc[mi][ni][r];
      }
}

// ---- final: d_out <- tmp, dtype per detected flag ----
__global__ __launch_bounds__(256) void final_kernel(
    const float* __restrict__ tmp, void* __restrict__ out,
    const int* __restrict__ flag)
{
  const int bf = *flag;
  size_t i = ((size_t)blockIdx.x * 256 + threadIdx.x) * 8;
  f32x4 lo = *(const f32x4*)(tmp + i);
  f32x4 hi = *(const f32x4*)(tmp + i + 4);
  if (bf) {
    bf16x8 r;
    r[0] = (short)f2bf(lo[0]); r[1] = (short)f2bf(lo[1]);
    r[2] = (short)f2bf(lo[2]); r[3] = (short)f2bf(lo[3]);
    r[4] = (short)f2bf(hi[0]); r[5] = (short)f2bf(hi[1]);
    r[6] = (short)f2bf(hi[2]); r[7] = (short)f2bf(hi[3]);
    *(bf16x8*)((unsigned short*)out + i) = r;
  } else {
    *(f32x4*)((float*)out + i) = lo;
    *(f32x4*)((float*)out + i + 4) = hi;
  }
}

extern "C" void kernel_launch(void* const* d_in, const int* in_sizes, int n_in,
                              void* d_out, int out_size, void* d_ws, size_t ws_size,
                              hipStream_t stream) {
  const void* X  = d_in[0];
  const void* Wq = d_in[1];
  const void* Wk = d_in[2];
  const void* Wv = d_in[3];
  const void* Wo = d_in[4];
  const int* causal = (const int*)d_in[5];

  const size_t NE = (size_t)2 * SEQ * D_MODEL;   // 4,194,304 elems
  const size_t WE = (size_t)D_MODEL * D_MODEL;   // 1,048,576 elems
  int* flag0 = (int*)d_ws;
  int* flag1 = flag0 + 1;
  unsigned short* kws = (unsigned short*)((char*)d_ws + 64);  // K  [b,h,s,d]  8MB
  unsigned short* vws = kws + NE;                             // V^T [b,h,d,s] 8MB
  float* tmp = (float*)kws;                                   // 16MB, overlays dead K+V
  unsigned short* Wb = vws + NE;                              // 4x bf16 W, 8MB (fast path)
  unsigned short* qd = (unsigned short*)d_out;                // Q bf16, d_out lower 8MB
  unsigned short* Xb = qd + NE;                               // X bf16, d_out upper 8MB

  const bool big = ws_size >= (size_t)64 + 24ull * 1024 * 1024;

  hipLaunchKernelGGL(detect_kernel, dim3(1), dim3(64), 0, stream,
                     (const unsigned short*)X, flag0);
  if (big) {
    hipLaunchKernelGGL(convert_kernel, dim3(2048, 5), dim3(256), 0, stream,
                       X, Wq, Wk, Wv, Wo, flag0, Xb, Wb);
    hipLaunchKernelGGL(qkv_kernel, dim3(8, 32, 3), dim3(256), 0, stream,
                       Xb, Wb, Wb + WE, Wb + 2 * WE, flag1, qd, kws, vws);
    hipLaunchKernelGGL(attn_kernel, dim3(16, 16, 2), dim3(256), 0, stream,
                       qd, kws, vws, causal);
    hipLaunchKernelGGL(oproj_kernel, dim3(8, 32), dim3(256), 0, stream,
                       qd, Wb + 3 * WE, flag1, tmp);
  } else {
    hipLaunchKernelGGL(qkv_kernel, dim3(8, 32, 3), dim3(256), 0, stream,
                       X, Wq, Wk, Wv, flag0, qd, kws, vws);
    hipLaunchKernelGGL(attn_kernel, dim3(16, 16, 2), dim3(256), 0, stream,
                       qd, kws, vws, causal);
    hipLaunchKernelGGL(oproj_kernel, dim3(8, 32), dim3(256), 0, stream,
                       qd, Wo, flag0, tmp);
  }
  hipLaunchKernelGGL(final_kernel, dim3(2048), dim3(256), 0, stream,
                     tmp, d_out, flag0);
}

// Round 5
// 251.892 us; speedup vs baseline: 2.1067x; 1.2321x over previous
//
#include <hip/hip_runtime.h>

typedef __attribute__((ext_vector_type(8))) short bf16x8;
typedef __attribute__((ext_vector_type(4))) float f32x4;
typedef __attribute__((ext_vector_type(4))) unsigned short u16x4;

#define MFMA16(a, b, c) __builtin_amdgcn_mfma_f32_16x16x32_bf16((a), (b), (c), 0, 0, 0)

static constexpr int D_MODEL = 1024;
static constexpr int SEQ = 2048;
static constexpr int NH = 16;
static constexpr int HD = 64;
static constexpr int LDA = 40;   // slow-path GEMM LDS row stride
static constexpr int PSTR = 80;  // attn P-buffer row stride (160B, b128-aligned)
static constexpr float NEG_BIG = -1.0e30f;

__device__ __forceinline__ unsigned short f2bf(float f) {
  union { float f; unsigned int u; } v; v.f = f;
  unsigned int r = v.u + 0x7fffu + ((v.u >> 16) & 1u);
  return (unsigned short)(r >> 16);
}

// Adaptive 8-element load: bf16 direct, or f32 -> RNE bf16 convert (slow path).
__device__ __forceinline__ bf16x8 ld8(const void* p, size_t eidx, int bf) {
  if (bf) return *(const bf16x8*)((const unsigned short*)p + eidx);
  const float* f = (const float*)p + eidx;
  f32x4 lo = *(const f32x4*)f;
  f32x4 hi = *(const f32x4*)(f + 4);
  bf16x8 r;
  r[0] = (short)f2bf(lo[0]); r[1] = (short)f2bf(lo[1]);
  r[2] = (short)f2bf(lo[2]); r[3] = (short)f2bf(lo[3]);
  r[4] = (short)f2bf(hi[0]); r[5] = (short)f2bf(hi[1]);
  r[6] = (short)f2bf(hi[2]); r[7] = (short)f2bf(hi[3]);
  return r;
}

// async global -> LDS, 16B per lane (dst = wave-uniform base + lane*16)
__device__ __forceinline__ void async16(const unsigned short* g, unsigned short* l) {
  __builtin_amdgcn_global_load_lds(
      (const __attribute__((address_space(1))) void*)g,
      (__attribute__((address_space(3))) void*)l, 16, 0, 0);
}

// ---- dtype detector ----
__global__ __launch_bounds__(64) void detect_kernel(
    const unsigned short* __restrict__ xs, int* __restrict__ flag) {
  int lane = threadIdx.x;
  unsigned short s = xs[2 * lane];
  int e = (s >> 7) & 0xFF;
  bool hit = (e >= 117 && e <= 129);
  unsigned long long m = __ballot(hit);
  if (lane == 0) { flag[0] = (__popcll(m) >= 32) ? 1 : 0; flag[1] = 1; }
}

// ---- pre-convert X and the four W matrices to bf16 (fast path) ----
__global__ __launch_bounds__(256) void convert_kernel(
    const void* __restrict__ X,
    const void* __restrict__ W0, const void* __restrict__ W1,
    const void* __restrict__ W2, const void* __restrict__ W3,
    const int* __restrict__ flag,
    unsigned short* __restrict__ Xb, unsigned short* __restrict__ Wb)
{
  const int bf = *flag;
  const int ty = blockIdx.y;
  const void* src; unsigned short* dst; size_t n;
  if (ty == 0) { src = X; dst = Xb; n = (size_t)2 * SEQ * D_MODEL; }
  else {
    src = (ty == 1) ? W0 : (ty == 2) ? W1 : (ty == 3) ? W2 : W3;
    dst = Wb + (size_t)(ty - 1) * D_MODEL * D_MODEL;
    n = (size_t)D_MODEL * D_MODEL;
  }
  size_t i = ((size_t)blockIdx.x * 256 + threadIdx.x) * 8;
  if (i >= n) return;
  *(bf16x8*)(dst + i) = ld8(src, i, bf);
}

// ======================= FAST PATH: m97-style bf16 GEMM =======================
// 128x128 tile, BK=32, global_load_lds width-16 staging into [128][32] LDS.
__device__ __forceinline__ void gemm_fast_core(
    const unsigned short* __restrict__ A, const unsigned short* __restrict__ B,
    int tm, int tn, unsigned short* As, unsigned short* Bs, f32x4 acc[4][4])
{
  const int t = threadIdx.x;
  const int lane = t & 63;
  const int w = t >> 6;
  const int wm = (w >> 1) * 64, wn = (w & 1) * 64;
  const int quad = lane >> 4, l16 = lane & 15;
  const int srow = lane >> 2;          // 16 rows per instruction, 4 lanes/row
  const int scol = (lane & 3) * 8;     // 8-elem (16B) chunk within the 32-elem row

#pragma unroll
  for (int mi = 0; mi < 4; ++mi)
#pragma unroll
    for (int ni = 0; ni < 4; ++ni)
      acc[mi][ni] = (f32x4){0.f, 0.f, 0.f, 0.f};

  for (int k0 = 0; k0 < D_MODEL; k0 += 32) {
    __syncthreads();  // previous iteration's fragment reads complete
#pragma unroll
    for (int j = 0; j < 2; ++j) {
      const int row = w * 32 + j * 16;
      async16(A + (size_t)(tm + row + srow) * D_MODEL + k0 + scol, As + row * 32);
      async16(B + (size_t)(tn + row + srow) * D_MODEL + k0 + scol, Bs + row * 32);
    }
    asm volatile("s_waitcnt vmcnt(0)" ::: "memory");
    __syncthreads();
    bf16x8 af[4], bfv[4];
#pragma unroll
    for (int mi = 0; mi < 4; ++mi)
      af[mi] = *(const bf16x8*)(As + (wm + mi * 16 + l16) * 32 + quad * 8);
#pragma unroll
    for (int ni = 0; ni < 4; ++ni)
      bfv[ni] = *(const bf16x8*)(Bs + (wn + ni * 16 + l16) * 32 + quad * 8);
#pragma unroll
    for (int mi = 0; mi < 4; ++mi)
#pragma unroll
      for (int ni = 0; ni < 4; ++ni)
        acc[mi][ni] = MFMA16(af[mi], bfv[ni], acc[mi][ni]);
  }
}

__global__ __launch_bounds__(256) void qkv_fast_kernel(
    const unsigned short* __restrict__ X,
    const unsigned short* __restrict__ Wb,   // [3][1024][1024] bf16 (q,k,v)
    unsigned short* __restrict__ qd,
    unsigned short* __restrict__ kws,
    unsigned short* __restrict__ vws)
{
  __shared__ __align__(16) unsigned short As[128 * 32];
  __shared__ __align__(16) unsigned short Bs[128 * 32];
  const int z = blockIdx.z;
  const unsigned short* W = Wb + (size_t)z * D_MODEL * D_MODEL;
  const int tm = blockIdx.y * 128, tn = blockIdx.x * 128;
  f32x4 acc[4][4];
  gemm_fast_core(X, W, tm, tn, As, Bs, acc);

  const int t = threadIdx.x;
  const int lane = t & 63, w = t >> 6;
  const int wm = (w >> 1) * 64, wn = (w & 1) * 64;
  const int quad = lane >> 4, l16 = lane & 15;
#pragma unroll
  for (int mi = 0; mi < 4; ++mi)
#pragma unroll
    for (int ni = 0; ni < 4; ++ni)
#pragma unroll
      for (int r = 0; r < 4; ++r) {
        int m = tm + wm + mi * 16 + quad * 4 + r;
        int n = tn + wn + ni * 16 + l16;
        unsigned short bv = f2bf(acc[mi][ni][r]);
        if (z == 0) {
          qd[(size_t)m * D_MODEL + n] = bv;
        } else {
          int b = m >> 11, s = m & 2047;
          int h = n >> 6, d = n & 63;
          if (z == 1) kws[(((size_t)b * NH + h) * SEQ + s) * HD + d] = bv;
          else        vws[(((size_t)b * NH + h) * HD + d) * SEQ + s] = bv;
        }
      }
}

__global__ __launch_bounds__(256) void oproj_fast_kernel(
    const unsigned short* __restrict__ AW,
    const unsigned short* __restrict__ Wo,
    float* __restrict__ tmp)
{
  __shared__ __align__(16) unsigned short As[128 * 32];
  __shared__ __align__(16) unsigned short Bs[128 * 32];
  const int tm = blockIdx.y * 128, tn = blockIdx.x * 128;
  f32x4 acc[4][4];
  gemm_fast_core(AW, Wo, tm, tn, As, Bs, acc);

  const int t = threadIdx.x;
  const int lane = t & 63, w = t >> 6;
  const int wm = (w >> 1) * 64, wn = (w & 1) * 64;
  const int quad = lane >> 4, l16 = lane & 15;
#pragma unroll
  for (int mi = 0; mi < 4; ++mi)
#pragma unroll
    for (int ni = 0; ni < 4; ++ni)
#pragma unroll
      for (int r = 0; r < 4; ++r) {
        int m = tm + wm + mi * 16 + quad * 4 + r;
        int n = tn + wn + ni * 16 + l16;
        tmp[(size_t)m * D_MODEL + n] = acc[mi][ni][r];
      }
}

// ======================= SLOW PATH GEMM (dtype-adaptive) =======================
__device__ __forceinline__ void gemm_tile_128x128(
    const void* __restrict__ A, const void* __restrict__ B, int bf,
    int tm, int tn, unsigned short* As, unsigned short* Bs, f32x4 acc[4][4])
{
  const int t = threadIdx.x;
  const int lane = t & 63;
  const int w = t >> 6;
  const int wm = (w >> 1) * 64, wn = (w & 1) * 64;
  const int quad = lane >> 4, l16 = lane & 15;
  const int r0 = t >> 2, kc = (t & 3) * 8;
  const int r1 = r0 + 64;

#pragma unroll
  for (int mi = 0; mi < 4; ++mi)
#pragma unroll
    for (int ni = 0; ni < 4; ++ni)
      acc[mi][ni] = (f32x4){0.f, 0.f, 0.f, 0.f};

  for (int k0 = 0; k0 < D_MODEL; k0 += 32) {
    bf16x8 a0 = ld8(A, (size_t)(tm + r0) * D_MODEL + k0 + kc, bf);
    bf16x8 a1 = ld8(A, (size_t)(tm + r1) * D_MODEL + k0 + kc, bf);
    bf16x8 b0 = ld8(B, (size_t)(tn + r0) * D_MODEL + k0 + kc, bf);
    bf16x8 b1 = ld8(B, (size_t)(tn + r1) * D_MODEL + k0 + kc, bf);
    __syncthreads();
    *(bf16x8*)(As + r0 * LDA + kc) = a0;
    *(bf16x8*)(As + r1 * LDA + kc) = a1;
    *(bf16x8*)(Bs + r0 * LDA + kc) = b0;
    *(bf16x8*)(Bs + r1 * LDA + kc) = b1;
    __syncthreads();
    bf16x8 af[4], bfv[4];
#pragma unroll
    for (int mi = 0; mi < 4; ++mi)
      af[mi] = *(const bf16x8*)(As + (wm + mi * 16 + l16) * LDA + quad * 8);
#pragma unroll
    for (int ni = 0; ni < 4; ++ni)
      bfv[ni] = *(const bf16x8*)(Bs + (wn + ni * 16 + l16) * LDA + quad * 8);
#pragma unroll
    for (int mi = 0; mi < 4; ++mi)
#pragma unroll
      for (int ni = 0; ni < 4; ++ni)
        acc[mi][ni] = MFMA16(af[mi], bfv[ni], acc[mi][ni]);
  }
}

__global__ __launch_bounds__(256) void qkv_kernel(
    const void* __restrict__ X,
    const void* __restrict__ Wq,
    const void* __restrict__ Wk,
    const void* __restrict__ Wv,
    const int* __restrict__ flag,
    unsigned short* __restrict__ qd,
    unsigned short* __restrict__ kws,
    unsigned short* __restrict__ vws)
{
  __shared__ __align__(16) unsigned short As[128 * LDA];
  __shared__ __align__(16) unsigned short Bs[128 * LDA];
  const int bf = *flag;
  const int z = blockIdx.z;
  const void* W = (z == 0) ? Wq : ((z == 1) ? Wk : Wv);
  const int tm = blockIdx.y * 128, tn = blockIdx.x * 128;
  f32x4 acc[4][4];
  gemm_tile_128x128(X, W, bf, tm, tn, As, Bs, acc);

  const int t = threadIdx.x;
  const int lane = t & 63, w = t >> 6;
  const int wm = (w >> 1) * 64, wn = (w & 1) * 64;
  const int quad = lane >> 4, l16 = lane & 15;
#pragma unroll
  for (int mi = 0; mi < 4; ++mi)
#pragma unroll
    for (int ni = 0; ni < 4; ++ni)
#pragma unroll
      for (int r = 0; r < 4; ++r) {
        int m = tm + wm + mi * 16 + quad * 4 + r;
        int n = tn + wn + ni * 16 + l16;
        unsigned short bv = f2bf(acc[mi][ni][r]);
        if (z == 0) {
          qd[(size_t)m * D_MODEL + n] = bv;
        } else {
          int b = m >> 11, s = m & 2047;
          int h = n >> 6, d = n & 63;
          if (z == 1) kws[(((size_t)b * NH + h) * SEQ + s) * HD + d] = bv;
          else        vws[(((size_t)b * NH + h) * HD + d) * SEQ + s] = bv;
        }
      }
}

__global__ __launch_bounds__(256) void oproj_kernel(
    const unsigned short* __restrict__ AW,
    const void* __restrict__ Wo,
    const int* __restrict__ flag,
    float* __restrict__ tmp)
{
  __shared__ __align__(16) unsigned short As[128 * LDA];
  __shared__ __align__(16) unsigned short Bs[128 * LDA];
  const int bf = *flag;
  const int t = threadIdx.x;
  const int lane = t & 63;
  const int w = t >> 6;
  const int wm = (w >> 1) * 64, wn = (w & 1) * 64;
  const int quad = lane >> 4, l16 = lane & 15;
  const int r0 = t >> 2, kc = (t & 3) * 8;
  const int r1 = r0 + 64;
  const int tm = blockIdx.y * 128, tn = blockIdx.x * 128;
  f32x4 acc[4][4];
#pragma unroll
  for (int mi = 0; mi < 4; ++mi)
#pragma unroll
    for (int ni = 0; ni < 4; ++ni)
      acc[mi][ni] = (f32x4){0.f, 0.f, 0.f, 0.f};

  for (int k0 = 0; k0 < D_MODEL; k0 += 32) {
    bf16x8 a0 = *(const bf16x8*)(AW + (size_t)(tm + r0) * D_MODEL + k0 + kc);
    bf16x8 a1 = *(const bf16x8*)(AW + (size_t)(tm + r1) * D_MODEL + k0 + kc);
    bf16x8 b0 = ld8(Wo, (size_t)(tn + r0) * D_MODEL + k0 + kc, bf);
    bf16x8 b1 = ld8(Wo, (size_t)(tn + r1) * D_MODEL + k0 + kc, bf);
    __syncthreads();
    *(bf16x8*)(As + r0 * LDA + kc) = a0;
    *(bf16x8*)(As + r1 * LDA + kc) = a1;
    *(bf16x8*)(Bs + r0 * LDA + kc) = b0;
    *(bf16x8*)(Bs + r1 * LDA + kc) = b1;
    __syncthreads();
    bf16x8 af[4], bfv[4];
#pragma unroll
    for (int mi = 0; mi < 4; ++mi)
      af[mi] = *(const bf16x8*)(As + (wm + mi * 16 + l16) * LDA + quad * 8);
#pragma unroll
    for (int ni = 0; ni < 4; ++ni)
      bfv[ni] = *(const bf16x8*)(Bs + (wn + ni * 16 + l16) * LDA + quad * 8);
#pragma unroll
    for (int mi = 0; mi < 4; ++mi)
#pragma unroll
      for (int ni = 0; ni < 4; ++ni)
        acc[mi][ni] = MFMA16(af[mi], bfv[ni], acc[mi][ni]);
  }
#pragma unroll
  for (int mi = 0; mi < 4; ++mi)
#pragma unroll
    for (int ni = 0; ni < 4; ++ni)
#pragma unroll
      for (int r = 0; r < 4; ++r) {
        int m = tm + wm + mi * 16 + quad * 4 + r;
        int n = tn + wn + ni * 16 + l16;
        tmp[(size_t)m * D_MODEL + n] = acc[mi][ni][r];
      }
}

// ======================= Flash attention =======================
// Block = 128 threads (2 waves); wave owns 32 q-rows (2 strips of 16).
// Balanced causal pairing over 32 groups of 64 rows: block does (bx, 31-bx).
// XCD-swizzled blockIdx: all 16 blocks of one (b,h) on one XCD (L2 locality).
__global__ __launch_bounds__(128, 2) void attn_kernel(
    unsigned short* __restrict__ Qd,   // Q in (plain [m,n]), attn-out in place
    const unsigned short* __restrict__ Kb,
    const unsigned short* __restrict__ Vt,
    const int* __restrict__ causal_p)
{
  __shared__ __align__(16) unsigned short pbuf[2 * 2 * 16 * PSTR];
  const int bid = blockIdx.x;
  const int xcd = bid & 7, slot = bid >> 3;
  const int bh = xcd * 4 + (slot >> 4);
  const int bx = slot & 15;
  const int b = bh >> 4, h = bh & 15;
  const int t = threadIdx.x, lane = t & 63, w = t >> 6;
  const int quad = lane >> 4, l16 = lane & 15;
  const int causal = *causal_p;
  unsigned short* qh = Qd + (size_t)b * SEQ * D_MODEL + h * HD;  // row stride D_MODEL
  const unsigned short* kh = Kb + ((size_t)b * NH + h) * SEQ * HD;
  const unsigned short* vh = Vt + ((size_t)b * NH + h) * HD * SEQ;
  const float Cs = 0.125f * 1.4426950408889634f;  // scale * log2(e)

  for (int hlf = 0; hlf < 2; ++hlf) {
    const int g = hlf ? (31 - bx) : bx;   // 64-row q group
    const int q0 = g * 64 + w * 32;       // wave's rows; strips at q0, q0+16

    bf16x8 aq[2][2];
#pragma unroll
    for (int s = 0; s < 2; ++s)
#pragma unroll
      for (int ch = 0; ch < 2; ++ch)
        aq[s][ch] = *(const bf16x8*)(qh + (size_t)(q0 + s * 16 + l16) * D_MODEL +
                                     ch * 32 + quad * 8);

    f32x4 oaccT[2][4];
#pragma unroll
    for (int s = 0; s < 2; ++s)
#pragma unroll
      for (int db = 0; db < 4; ++db) oaccT[s][db] = (f32x4){0.f, 0.f, 0.f, 0.f};
    float mI[2] = {NEG_BIG, NEG_BIG}, lsum[2] = {0.f, 0.f};
    const int ktend = causal ? (g + 1) : (SEQ / 64);

    // preload K(0) fragments (A-operand: lane l16 = kv row, k = d)
    bf16x8 kfr[4][2];
#pragma unroll
    for (int cb = 0; cb < 4; ++cb)
#pragma unroll
      for (int hf = 0; hf < 2; ++hf)
        kfr[cb][hf] = *(const bf16x8*)(kh + (size_t)(cb * 16 + l16) * HD +
                                       hf * 32 + quad * 8);

    for (int kt = 0; kt < ktend; ++kt) {
      // S^T = K·Q^T : C col = q (l16), row = kv (quad*4+r)
      f32x4 sc[2][4];
#pragma unroll
      for (int s = 0; s < 2; ++s)
#pragma unroll
        for (int cb = 0; cb < 4; ++cb) {
          sc[s][cb] = (f32x4){0.f, 0.f, 0.f, 0.f};
          sc[s][cb] = MFMA16(kfr[cb][0], aq[s][0], sc[s][cb]);
          sc[s][cb] = MFMA16(kfr[cb][1], aq[s][1], sc[s][cb]);
        }
      // prefetch V(kt) (A-operand: lane l16 = d row of V^T, k = kv)
      bf16x8 vfr[4][2];
#pragma unroll
      for (int db = 0; db < 4; ++db)
#pragma unroll
        for (int hf = 0; hf < 2; ++hf)
          vfr[db][hf] = *(const bf16x8*)(vh + (size_t)(db * 16 + l16) * SEQ +
                                         kt * 64 + hf * 32 + quad * 8);
      // prefetch K(kt+1)
      bf16x8 knx[4][2];
      if (kt + 1 < ktend) {
#pragma unroll
        for (int cb = 0; cb < 4; ++cb)
#pragma unroll
          for (int hf = 0; hf < 2; ++hf)
            knx[cb][hf] = *(const bf16x8*)(kh + (size_t)((kt + 1) * 64 + cb * 16 + l16) * HD +
                                           hf * 32 + quad * 8);
      }
      // causal mask on the diagonal tile
      if (causal && kt == g) {
#pragma unroll
        for (int s = 0; s < 2; ++s) {
          int q = q0 + s * 16 + l16;
#pragma unroll
          for (int cb = 0; cb < 4; ++cb)
#pragma unroll
            for (int r = 0; r < 4; ++r)
              if (kt * 64 + cb * 16 + quad * 4 + r > q) sc[s][cb][r] = NEG_BIG;
        }
      }
      // online softmax per strip; each lane owns one q column
#pragma unroll
      for (int s = 0; s < 2; ++s) {
        unsigned short* pw = pbuf + ((w * 2 + s) * 16) * PSTR;
        float mx = sc[s][0][0];
#pragma unroll
        for (int cb = 0; cb < 4; ++cb)
#pragma unroll
          for (int r = 0; r < 4; ++r) mx = fmaxf(mx, sc[s][cb][r]);
        mx = fmaxf(mx, __shfl_xor(mx, 16, 64));
        mx = fmaxf(mx, __shfl_xor(mx, 32, 64));
        float mn = fmaxf(mI[s], mx);
        float alpha = __builtin_amdgcn_exp2f((mI[s] - mn) * Cs);
        float mc = mn * Cs;
        mI[s] = mn;
        float ls = 0.f;
#pragma unroll
        for (int cb = 0; cb < 4; ++cb) {
          u16x4 pk;
#pragma unroll
          for (int r = 0; r < 4; ++r) {
            float p = __builtin_amdgcn_exp2f(sc[s][cb][r] * Cs - mc);
            ls += p;
            pk[r] = f2bf(p);
          }
          *(u16x4*)(pw + l16 * PSTR + cb * 16 + quad * 4) = pk;
        }
        lsum[s] = lsum[s] * alpha + ls;
#pragma unroll
        for (int db = 0; db < 4; ++db) {
          oaccT[s][db][0] *= alpha; oaccT[s][db][1] *= alpha;
          oaccT[s][db][2] *= alpha; oaccT[s][db][3] *= alpha;
        }
      }
      asm volatile("s_waitcnt lgkmcnt(0)" ::: "memory");  // P writes done (per-wave)
#pragma unroll
      for (int s = 0; s < 2; ++s) {
        unsigned short* pw = pbuf + ((w * 2 + s) * 16) * PSTR;
        bf16x8 bp[2];
#pragma unroll
        for (int hf = 0; hf < 2; ++hf)
          bp[hf] = *(const bf16x8*)(pw + l16 * PSTR + hf * 32 + quad * 8);
#pragma unroll
        for (int db = 0; db < 4; ++db) {
          oaccT[s][db] = MFMA16(vfr[db][0], bp[0], oaccT[s][db]);
          oaccT[s][db] = MFMA16(vfr[db][1], bp[1], oaccT[s][db]);
        }
      }
#pragma unroll
      for (int cb = 0; cb < 4; ++cb)
#pragma unroll
        for (int hf = 0; hf < 2; ++hf)
          kfr[cb][hf] = knx[cb][hf];
    }
    // epilogue per strip
#pragma unroll
    for (int s = 0; s < 2; ++s) {
      float l = lsum[s];
      l += __shfl_xor(l, 16, 64);
      l += __shfl_xor(l, 32, 64);
      float inv = 1.0f / l;
#pragma unroll
      for (int db = 0; db < 4; ++db) {
        u16x4 o;
#pragma unroll
        for (int r = 0; r < 4; ++r) o[r] = f2bf(oaccT[s][db][r] * inv);
        *(u16x4*)(qh + (size_t)(q0 + s * 16 + l16) * D_MODEL + db * 16 + quad * 4) = o;
      }
    }
  }
}

// ---- final: d_out <- tmp, dtype per detected flag ----
__global__ __launch_bounds__(256) void final_kernel(
    const float* __restrict__ tmp, void* __restrict__ out,
    const int* __restrict__ flag)
{
  const int bf = *flag;
  size_t i = ((size_t)blockIdx.x * 256 + threadIdx.x) * 8;
  f32x4 lo = *(const f32x4*)(tmp + i);
  f32x4 hi = *(const f32x4*)(tmp + i + 4);
  if (bf) {
    bf16x8 r;
    r[0] = (short)f2bf(lo[0]); r[1] = (short)f2bf(lo[1]);
    r[2] = (short)f2bf(lo[2]); r[3] = (short)f2bf(lo[3]);
    r[4] = (short)f2bf(hi[0]); r[5] = (short)f2bf(hi[1]);
    r[6] = (short)f2bf(hi[2]); r[7] = (short)f2bf(hi[3]);
    *(bf16x8*)((unsigned short*)out + i) = r;
  } else {
    *(f32x4*)((float*)out + i) = lo;
    *(f32x4*)((float*)out + i + 4) = hi;
  }
}

extern "C" void kernel_launch(void* const* d_in, const int* in_sizes, int n_in,
                              void* d_out, int out_size, void* d_ws, size_t ws_size,
                              hipStream_t stream) {
  const void* X  = d_in[0];
  const void* Wq = d_in[1];
  const void* Wk = d_in[2];
  const void* Wv = d_in[3];
  const void* Wo = d_in[4];
  const int* causal = (const int*)d_in[5];

  const size_t NE = (size_t)2 * SEQ * D_MODEL;   // 4,194,304 elems
  const size_t WE = (size_t)D_MODEL * D_MODEL;   // 1,048,576 elems
  int* flag0 = (int*)d_ws;
  int* flag1 = flag0 + 1;
  unsigned short* kws = (unsigned short*)((char*)d_ws + 64);  // K  [b,h,s,d]  8MB
  unsigned short* vws = kws + NE;                             // V^T [b,h,d,s] 8MB
  float* tmp = (float*)kws;                                   // 16MB over dead K+V
  unsigned short* Wb = vws + NE;                              // 4x bf16 W, 8MB
  unsigned short* qd = (unsigned short*)d_out;                // Q bf16, lower 8MB
  unsigned short* Xb = qd + NE;                               // X bf16, upper 8MB (f32 out)

  const bool big = ws_size >= (size_t)64 + 24ull * 1024 * 1024;

  hipLaunchKernelGGL(detect_kernel, dim3(1), dim3(64), 0, stream,
                     (const unsigned short*)X, flag0);
  if (big) {
    hipLaunchKernelGGL(convert_kernel, dim3(2048, 5), dim3(256), 0, stream,
                       X, Wq, Wk, Wv, Wo, flag0, Xb, Wb);
    hipLaunchKernelGGL(qkv_fast_kernel, dim3(8, 32, 3), dim3(256), 0, stream,
                       Xb, Wb, qd, kws, vws);
    hipLaunchKernelGGL(attn_kernel, dim3(512), dim3(128), 0, stream,
                       qd, kws, vws, causal);
    hipLaunchKernelGGL(oproj_fast_kernel, dim3(8, 32), dim3(256), 0, stream,
                       qd, Wb + 3 * WE, tmp);
  } else {
    hipLaunchKernelGGL(qkv_kernel, dim3(8, 32, 3), dim3(256), 0, stream,
                       X, Wq, Wk, Wv, flag0, qd, kws, vws);
    hipLaunchKernelGGL(attn_kernel, dim3(512), dim3(128), 0, stream,
                       qd, kws, vws, causal);
    hipLaunchKernelGGL(oproj_kernel, dim3(8, 32), dim3(256), 0, stream,
                       qd, Wo, flag0, tmp);
  }
  hipLaunchKernelGGL(final_kernel, dim3(2048), dim3(256), 0, stream,
                     tmp, d_out, flag0);
}

// Round 6
// 238.581 us; speedup vs baseline: 2.2243x; 1.0558x over previous
//
#include <hip/hip_runtime.h>

typedef __attribute__((ext_vector_type(8))) short bf16x8;
typedef __attribute__((ext_vector_type(4))) float f32x4;
typedef __attribute__((ext_vector_type(4))) unsigned short u16x4;

#define MFMA16(a, b, c) __builtin_amdgcn_mfma_f32_16x16x32_bf16((a), (b), (c), 0, 0, 0)

static constexpr int D_MODEL = 1024;
static constexpr int SEQ = 2048;
static constexpr int NH = 16;
static constexpr int HD = 64;
static constexpr int LDA = 40;   // slow-path GEMM LDS row stride
static constexpr int PSTR = 80;  // attn P-buffer row stride (160B, b128-aligned)
static constexpr float NEG_BIG = -1.0e30f;

__device__ __forceinline__ unsigned short f2bf(float f) {
  union { float f; unsigned int u; } v; v.f = f;
  unsigned int r = v.u + 0x7fffu + ((v.u >> 16) & 1u);
  return (unsigned short)(r >> 16);
}

// Adaptive 8-element load: bf16 direct, or f32 -> RNE bf16 convert (slow path).
__device__ __forceinline__ bf16x8 ld8(const void* p, size_t eidx, int bf) {
  if (bf) return *(const bf16x8*)((const unsigned short*)p + eidx);
  const float* f = (const float*)p + eidx;
  f32x4 lo = *(const f32x4*)f;
  f32x4 hi = *(const f32x4*)(f + 4);
  bf16x8 r;
  r[0] = (short)f2bf(lo[0]); r[1] = (short)f2bf(lo[1]);
  r[2] = (short)f2bf(lo[2]); r[3] = (short)f2bf(lo[3]);
  r[4] = (short)f2bf(hi[0]); r[5] = (short)f2bf(hi[1]);
  r[6] = (short)f2bf(hi[2]); r[7] = (short)f2bf(hi[3]);
  return r;
}

// async global -> LDS, 16B per lane (dst = wave-uniform base + lane*16)
__device__ __forceinline__ void async16(const unsigned short* g, unsigned short* l) {
  __builtin_amdgcn_global_load_lds(
      (const __attribute__((address_space(1))) void*)g,
      (__attribute__((address_space(3))) void*)l, 16, 0, 0);
}

// ---- dtype detector ----
__global__ __launch_bounds__(64) void detect_kernel(
    const unsigned short* __restrict__ xs, int* __restrict__ flag) {
  int lane = threadIdx.x;
  unsigned short s = xs[2 * lane];
  int e = (s >> 7) & 0xFF;
  bool hit = (e >= 117 && e <= 129);
  unsigned long long m = __ballot(hit);
  if (lane == 0) { flag[0] = (__popcll(m) >= 32) ? 1 : 0; flag[1] = 1; }
}

// ---- pre-convert X and the four W matrices to bf16 (fast path) ----
__global__ __launch_bounds__(256) void convert_kernel(
    const void* __restrict__ X,
    const void* __restrict__ W0, const void* __restrict__ W1,
    const void* __restrict__ W2, const void* __restrict__ W3,
    const int* __restrict__ flag,
    unsigned short* __restrict__ Xb, unsigned short* __restrict__ Wb)
{
  const int bf = *flag;
  const int ty = blockIdx.y;
  const void* src; unsigned short* dst; size_t n;
  if (ty == 0) { src = X; dst = Xb; n = (size_t)2 * SEQ * D_MODEL; }
  else {
    src = (ty == 1) ? W0 : (ty == 2) ? W1 : (ty == 3) ? W2 : W3;
    dst = Wb + (size_t)(ty - 1) * D_MODEL * D_MODEL;
    n = (size_t)D_MODEL * D_MODEL;
  }
  size_t i = ((size_t)blockIdx.x * 256 + threadIdx.x) * 8;
  if (i >= n) return;
  *(bf16x8*)(dst + i) = ld8(src, i, bf);
}

// ======================= FAST PATH bf16 GEMM =======================
// 128x128 tile, BK=64, global_load_lds width-16 staging into [128][64] LDS
// with XOR-chunk swizzle: LDS[r][c] = global[r][c ^ (r&7)], which puts the
// fragment ds_read_b128 of a quad's 16 lanes on all 32 banks (2-way = free).
__device__ __forceinline__ void gemm_fast_core(
    const unsigned short* __restrict__ A, const unsigned short* __restrict__ B,
    int tm, int tn, unsigned short* As, unsigned short* Bs, f32x4 acc[4][4])
{
  const int t = threadIdx.x;
  const int lane = t & 63;
  const int w = t >> 6;
  const int wm = (w >> 1) * 64, wn = (w & 1) * 64;
  const int quad = lane >> 4, l16 = lane & 15;
  const int srow = lane >> 3;                    // 8 rows per async16 instr
  const int scol = ((lane & 7) ^ srow) * 8;      // swizzled global chunk
  const int xa = l16 & 7;                        // read-side swizzle key

#pragma unroll
  for (int mi = 0; mi < 4; ++mi)
#pragma unroll
    for (int ni = 0; ni < 4; ++ni)
      acc[mi][ni] = (f32x4){0.f, 0.f, 0.f, 0.f};

  for (int k0 = 0; k0 < D_MODEL; k0 += 64) {
    __syncthreads();  // previous iteration's fragment reads complete
#pragma unroll
    for (int j = 0; j < 4; ++j) {
      const int row = w * 32 + j * 8;
      async16(A + (size_t)(tm + row + srow) * D_MODEL + k0 + scol, As + row * 64);
      async16(B + (size_t)(tn + row + srow) * D_MODEL + k0 + scol, Bs + row * 64);
    }
    asm volatile("s_waitcnt vmcnt(0)" ::: "memory");
    __syncthreads();
    bf16x8 af[2][4], bfv[2][4];
#pragma unroll
    for (int ks = 0; ks < 2; ++ks) {
#pragma unroll
      for (int mi = 0; mi < 4; ++mi)
        af[ks][mi] = *(const bf16x8*)(As + (wm + mi * 16 + l16) * 64 +
                                      ((ks * 4 + quad) ^ xa) * 8);
#pragma unroll
      for (int ni = 0; ni < 4; ++ni)
        bfv[ks][ni] = *(const bf16x8*)(Bs + (wn + ni * 16 + l16) * 64 +
                                       ((ks * 4 + quad) ^ xa) * 8);
    }
#pragma unroll
    for (int ks = 0; ks < 2; ++ks)
#pragma unroll
      for (int mi = 0; mi < 4; ++mi)
#pragma unroll
        for (int ni = 0; ni < 4; ++ni)
          acc[mi][ni] = MFMA16(af[ks][mi], bfv[ks][ni], acc[mi][ni]);
  }
}

__global__ __launch_bounds__(256) void qkv_fast_kernel(
    const unsigned short* __restrict__ X,
    const unsigned short* __restrict__ Wb,   // [3][1024][1024] bf16 (q,k,v)
    unsigned short* __restrict__ qd,
    unsigned short* __restrict__ kws,
    unsigned short* __restrict__ vws)
{
  __shared__ __align__(16) unsigned short As[128 * 64];
  __shared__ __align__(16) unsigned short Bs[128 * 64];
  const int z = blockIdx.z;
  const unsigned short* W = Wb + (size_t)z * D_MODEL * D_MODEL;
  const int tm = blockIdx.y * 128, tn = blockIdx.x * 128;
  f32x4 acc[4][4];
  gemm_fast_core(X, W, tm, tn, As, Bs, acc);

  const int t = threadIdx.x;
  const int lane = t & 63, w = t >> 6;
  const int wm = (w >> 1) * 64, wn = (w & 1) * 64;
  const int quad = lane >> 4, l16 = lane & 15;
#pragma unroll
  for (int mi = 0; mi < 4; ++mi)
#pragma unroll
    for (int ni = 0; ni < 4; ++ni)
#pragma unroll
      for (int r = 0; r < 4; ++r) {
        int m = tm + wm + mi * 16 + quad * 4 + r;
        int n = tn + wn + ni * 16 + l16;
        unsigned short bv = f2bf(acc[mi][ni][r]);
        if (z == 0) {
          qd[(size_t)m * D_MODEL + n] = bv;
        } else {
          int b = m >> 11, s = m & 2047;
          int h = n >> 6, d = n & 63;
          if (z == 1) kws[(((size_t)b * NH + h) * SEQ + s) * HD + d] = bv;
          else        vws[(((size_t)b * NH + h) * HD + d) * SEQ + s] = bv;
        }
      }
}

__global__ __launch_bounds__(256) void oproj_fast_kernel(
    const unsigned short* __restrict__ AW,
    const unsigned short* __restrict__ Wo,
    float* __restrict__ tmp)
{
  __shared__ __align__(16) unsigned short As[128 * 64];
  __shared__ __align__(16) unsigned short Bs[128 * 64];
  const int tm = blockIdx.y * 128, tn = blockIdx.x * 128;
  f32x4 acc[4][4];
  gemm_fast_core(AW, Wo, tm, tn, As, Bs, acc);

  const int t = threadIdx.x;
  const int lane = t & 63, w = t >> 6;
  const int wm = (w >> 1) * 64, wn = (w & 1) * 64;
  const int quad = lane >> 4, l16 = lane & 15;
#pragma unroll
  for (int mi = 0; mi < 4; ++mi)
#pragma unroll
    for (int ni = 0; ni < 4; ++ni)
#pragma unroll
      for (int r = 0; r < 4; ++r) {
        int m = tm + wm + mi * 16 + quad * 4 + r;
        int n = tn + wn + ni * 16 + l16;
        tmp[(size_t)m * D_MODEL + n] = acc[mi][ni][r];
      }
}

// ======================= SLOW PATH GEMM (dtype-adaptive) =======================
__device__ __forceinline__ void gemm_tile_128x128(
    const void* __restrict__ A, const void* __restrict__ B, int bf,
    int tm, int tn, unsigned short* As, unsigned short* Bs, f32x4 acc[4][4])
{
  const int t = threadIdx.x;
  const int lane = t & 63;
  const int w = t >> 6;
  const int wm = (w >> 1) * 64, wn = (w & 1) * 64;
  const int quad = lane >> 4, l16 = lane & 15;
  const int r0 = t >> 2, kc = (t & 3) * 8;
  const int r1 = r0 + 64;

#pragma unroll
  for (int mi = 0; mi < 4; ++mi)
#pragma unroll
    for (int ni = 0; ni < 4; ++ni)
      acc[mi][ni] = (f32x4){0.f, 0.f, 0.f, 0.f};

  for (int k0 = 0; k0 < D_MODEL; k0 += 32) {
    bf16x8 a0 = ld8(A, (size_t)(tm + r0) * D_MODEL + k0 + kc, bf);
    bf16x8 a1 = ld8(A, (size_t)(tm + r1) * D_MODEL + k0 + kc, bf);
    bf16x8 b0 = ld8(B, (size_t)(tn + r0) * D_MODEL + k0 + kc, bf);
    bf16x8 b1 = ld8(B, (size_t)(tn + r1) * D_MODEL + k0 + kc, bf);
    __syncthreads();
    *(bf16x8*)(As + r0 * LDA + kc) = a0;
    *(bf16x8*)(As + r1 * LDA + kc) = a1;
    *(bf16x8*)(Bs + r0 * LDA + kc) = b0;
    *(bf16x8*)(Bs + r1 * LDA + kc) = b1;
    __syncthreads();
    bf16x8 af[4], bfv[4];
#pragma unroll
    for (int mi = 0; mi < 4; ++mi)
      af[mi] = *(const bf16x8*)(As + (wm + mi * 16 + l16) * LDA + quad * 8);
#pragma unroll
    for (int ni = 0; ni < 4; ++ni)
      bfv[ni] = *(const bf16x8*)(Bs + (wn + ni * 16 + l16) * LDA + quad * 8);
#pragma unroll
    for (int mi = 0; mi < 4; ++mi)
#pragma unroll
      for (int ni = 0; ni < 4; ++ni)
        acc[mi][ni] = MFMA16(af[mi], bfv[ni], acc[mi][ni]);
  }
}

__global__ __launch_bounds__(256) void qkv_kernel(
    const void* __restrict__ X,
    const void* __restrict__ Wq,
    const void* __restrict__ Wk,
    const void* __restrict__ Wv,
    const int* __restrict__ flag,
    unsigned short* __restrict__ qd,
    unsigned short* __restrict__ kws,
    unsigned short* __restrict__ vws)
{
  __shared__ __align__(16) unsigned short As[128 * LDA];
  __shared__ __align__(16) unsigned short Bs[128 * LDA];
  const int bf = *flag;
  const int z = blockIdx.z;
  const void* W = (z == 0) ? Wq : ((z == 1) ? Wk : Wv);
  const int tm = blockIdx.y * 128, tn = blockIdx.x * 128;
  f32x4 acc[4][4];
  gemm_tile_128x128(X, W, bf, tm, tn, As, Bs, acc);

  const int t = threadIdx.x;
  const int lane = t & 63, w = t >> 6;
  const int wm = (w >> 1) * 64, wn = (w & 1) * 64;
  const int quad = lane >> 4, l16 = lane & 15;
#pragma unroll
  for (int mi = 0; mi < 4; ++mi)
#pragma unroll
    for (int ni = 0; ni < 4; ++ni)
#pragma unroll
      for (int r = 0; r < 4; ++r) {
        int m = tm + wm + mi * 16 + quad * 4 + r;
        int n = tn + wn + ni * 16 + l16;
        unsigned short bv = f2bf(acc[mi][ni][r]);
        if (z == 0) {
          qd[(size_t)m * D_MODEL + n] = bv;
        } else {
          int b = m >> 11, s = m & 2047;
          int h = n >> 6, d = n & 63;
          if (z == 1) kws[(((size_t)b * NH + h) * SEQ + s) * HD + d] = bv;
          else        vws[(((size_t)b * NH + h) * HD + d) * SEQ + s] = bv;
        }
      }
}

__global__ __launch_bounds__(256) void oproj_kernel(
    const unsigned short* __restrict__ AW,
    const void* __restrict__ Wo,
    const int* __restrict__ flag,
    float* __restrict__ tmp)
{
  __shared__ __align__(16) unsigned short As[128 * LDA];
  __shared__ __align__(16) unsigned short Bs[128 * LDA];
  const int bf = *flag;
  const int t = threadIdx.x;
  const int lane = t & 63;
  const int w = t >> 6;
  const int wm = (w >> 1) * 64, wn = (w & 1) * 64;
  const int quad = lane >> 4, l16 = lane & 15;
  const int r0 = t >> 2, kc = (t & 3) * 8;
  const int r1 = r0 + 64;
  const int tm = blockIdx.y * 128, tn = blockIdx.x * 128;
  f32x4 acc[4][4];
#pragma unroll
  for (int mi = 0; mi < 4; ++mi)
#pragma unroll
    for (int ni = 0; ni < 4; ++ni)
      acc[mi][ni] = (f32x4){0.f, 0.f, 0.f, 0.f};

  for (int k0 = 0; k0 < D_MODEL; k0 += 32) {
    bf16x8 a0 = *(const bf16x8*)(AW + (size_t)(tm + r0) * D_MODEL + k0 + kc);
    bf16x8 a1 = *(const bf16x8*)(AW + (size_t)(tm + r1) * D_MODEL + k0 + kc);
    bf16x8 b0 = ld8(Wo, (size_t)(tn + r0) * D_MODEL + k0 + kc, bf);
    bf16x8 b1 = ld8(Wo, (size_t)(tn + r1) * D_MODEL + k0 + kc, bf);
    __syncthreads();
    *(bf16x8*)(As + r0 * LDA + kc) = a0;
    *(bf16x8*)(As + r1 * LDA + kc) = a1;
    *(bf16x8*)(Bs + r0 * LDA + kc) = b0;
    *(bf16x8*)(Bs + r1 * LDA + kc) = b1;
    __syncthreads();
    bf16x8 af[4], bfv[4];
#pragma unroll
    for (int mi = 0; mi < 4; ++mi)
      af[mi] = *(const bf16x8*)(As + (wm + mi * 16 + l16) * LDA + quad * 8);
#pragma unroll
    for (int ni = 0; ni < 4; ++ni)
      bfv[ni] = *(const bf16x8*)(Bs + (wn + ni * 16 + l16) * LDA + quad * 8);
#pragma unroll
    for (int mi = 0; mi < 4; ++mi)
#pragma unroll
      for (int ni = 0; ni < 4; ++ni)
        acc[mi][ni] = MFMA16(af[mi], bfv[ni], acc[mi][ni]);
  }
#pragma unroll
  for (int mi = 0; mi < 4; ++mi)
#pragma unroll
    for (int ni = 0; ni < 4; ++ni)
#pragma unroll
      for (int r = 0; r < 4; ++r) {
        int m = tm + wm + mi * 16 + quad * 4 + r;
        int n = tn + wn + ni * 16 + l16;
        tmp[(size_t)m * D_MODEL + n] = acc[mi][ni][r];
      }
}

// ======================= Flash attention =======================
// Block = 128 threads (2 waves); wave owns 32 q-rows (2 strips of 16).
// Balanced causal pairing over 32 groups of 64 rows: block does (bx, 31-bx).
// XCD-swizzled blockIdx: all 16 blocks of one (b,h) on one XCD (L2 locality).
__global__ __launch_bounds__(128, 2) void attn_kernel(
    unsigned short* __restrict__ Qd,   // Q in (plain [m,n]), attn-out in place
    const unsigned short* __restrict__ Kb,
    const unsigned short* __restrict__ Vt,
    const int* __restrict__ causal_p)
{
  __shared__ __align__(16) unsigned short pbuf[2 * 2 * 16 * PSTR];
  const int bid = blockIdx.x;
  const int xcd = bid & 7, slot = bid >> 3;
  const int bh = xcd * 4 + (slot >> 4);
  const int bx = slot & 15;
  const int b = bh >> 4, h = bh & 15;
  const int t = threadIdx.x, lane = t & 63, w = t >> 6;
  const int quad = lane >> 4, l16 = lane & 15;
  const int causal = *causal_p;
  unsigned short* qh = Qd + (size_t)b * SEQ * D_MODEL + h * HD;  // row stride D_MODEL
  const unsigned short* kh = Kb + ((size_t)b * NH + h) * SEQ * HD;
  const unsigned short* vh = Vt + ((size_t)b * NH + h) * HD * SEQ;
  const float Cs = 0.125f * 1.4426950408889634f;  // scale * log2(e)

  for (int hlf = 0; hlf < 2; ++hlf) {
    const int g = hlf ? (31 - bx) : bx;   // 64-row q group
    const int q0 = g * 64 + w * 32;       // wave's rows; strips at q0, q0+16

    bf16x8 aq[2][2];
#pragma unroll
    for (int s = 0; s < 2; ++s)
#pragma unroll
      for (int ch = 0; ch < 2; ++ch)
        aq[s][ch] = *(const bf16x8*)(qh + (size_t)(q0 + s * 16 + l16) * D_MODEL +
                                     ch * 32 + quad * 8);

    f32x4 oaccT[2][4];
#pragma unroll
    for (int s = 0; s < 2; ++s)
#pragma unroll
      for (int db = 0; db < 4; ++db) oaccT[s][db] = (f32x4){0.f, 0.f, 0.f, 0.f};
    float mI[2] = {NEG_BIG, NEG_BIG}, lsum[2] = {0.f, 0.f};
    const int ktend = causal ? (g + 1) : (SEQ / 64);

    // preload K(0) fragments (A-operand: lane l16 = kv row, k = d)
    bf16x8 kfr[4][2];
#pragma unroll
    for (int cb = 0; cb < 4; ++cb)
#pragma unroll
      for (int hf = 0; hf < 2; ++hf)
        kfr[cb][hf] = *(const bf16x8*)(kh + (size_t)(cb * 16 + l16) * HD +
                                       hf * 32 + quad * 8);

    for (int kt = 0; kt < ktend; ++kt) {
      // S^T = K·Q^T : C col = q (l16), row = kv (quad*4+r)
      f32x4 sc[2][4];
#pragma unroll
      for (int s = 0; s < 2; ++s)
#pragma unroll
        for (int cb = 0; cb < 4; ++cb) {
          sc[s][cb] = (f32x4){0.f, 0.f, 0.f, 0.f};
          sc[s][cb] = MFMA16(kfr[cb][0], aq[s][0], sc[s][cb]);
          sc[s][cb] = MFMA16(kfr[cb][1], aq[s][1], sc[s][cb]);
        }
      // prefetch V(kt) (A-operand: lane l16 = d row of V^T, k = kv)
      bf16x8 vfr[4][2];
#pragma unroll
      for (int db = 0; db < 4; ++db)
#pragma unroll
        for (int hf = 0; hf < 2; ++hf)
          vfr[db][hf] = *(const bf16x8*)(vh + (size_t)(db * 16 + l16) * SEQ +
                                         kt * 64 + hf * 32 + quad * 8);
      // prefetch K(kt+1)
      bf16x8 knx[4][2];
      if (kt + 1 < ktend) {
#pragma unroll
        for (int cb = 0; cb < 4; ++cb)
#pragma unroll
          for (int hf = 0; hf < 2; ++hf)
            knx[cb][hf] = *(const bf16x8*)(kh + (size_t)((kt + 1) * 64 + cb * 16 + l16) * HD +
                                           hf * 32 + quad * 8);
      }
      // causal mask on the diagonal tile
      if (causal && kt == g) {
#pragma unroll
        for (int s = 0; s < 2; ++s) {
          int q = q0 + s * 16 + l16;
#pragma unroll
          for (int cb = 0; cb < 4; ++cb)
#pragma unroll
            for (int r = 0; r < 4; ++r)
              if (kt * 64 + cb * 16 + quad * 4 + r > q) sc[s][cb][r] = NEG_BIG;
        }
      }
      // online softmax per strip; each lane owns one q column
#pragma unroll
      for (int s = 0; s < 2; ++s) {
        unsigned short* pw = pbuf + ((w * 2 + s) * 16) * PSTR;
        float mx = sc[s][0][0];
#pragma unroll
        for (int cb = 0; cb < 4; ++cb)
#pragma unroll
          for (int r = 0; r < 4; ++r) mx = fmaxf(mx, sc[s][cb][r]);
        mx = fmaxf(mx, __shfl_xor(mx, 16, 64));
        mx = fmaxf(mx, __shfl_xor(mx, 32, 64));
        float mn = fmaxf(mI[s], mx);
        float alpha = __builtin_amdgcn_exp2f((mI[s] - mn) * Cs);
        float mc = mn * Cs;
        mI[s] = mn;
        float ls = 0.f;
#pragma unroll
        for (int cb = 0; cb < 4; ++cb) {
          u16x4 pk;
#pragma unroll
          for (int r = 0; r < 4; ++r) {
            float p = __builtin_amdgcn_exp2f(sc[s][cb][r] * Cs - mc);
            ls += p;
            pk[r] = f2bf(p);
          }
          *(u16x4*)(pw + l16 * PSTR + cb * 16 + quad * 4) = pk;
        }
        lsum[s] = lsum[s] * alpha + ls;
#pragma unroll
        for (int db = 0; db < 4; ++db) {
          oaccT[s][db][0] *= alpha; oaccT[s][db][1] *= alpha;
          oaccT[s][db][2] *= alpha; oaccT[s][db][3] *= alpha;
        }
      }
      asm volatile("s_waitcnt lgkmcnt(0)" ::: "memory");  // P writes done (per-wave)
#pragma unroll
      for (int s = 0; s < 2; ++s) {
        unsigned short* pw = pbuf + ((w * 2 + s) * 16) * PSTR;
        bf16x8 bp[2];
#pragma unroll
        for (int hf = 0; hf < 2; ++hf)
          bp[hf] = *(const bf16x8*)(pw + l16 * PSTR + hf * 32 + quad * 8);
#pragma unroll
        for (int db = 0; db < 4; ++db) {
          oaccT[s][db] = MFMA16(vfr[db][0], bp[0], oaccT[s][db]);
          oaccT[s][db] = MFMA16(vfr[db][1], bp[1], oaccT[s][db]);
        }
      }
#pragma unroll
      for (int cb = 0; cb < 4; ++cb)
#pragma unroll
        for (int hf = 0; hf < 2; ++hf)
          kfr[cb][hf] = knx[cb][hf];
    }
    // epilogue per strip
#pragma unroll
    for (int s = 0; s < 2; ++s) {
      float l = lsum[s];
      l += __shfl_xor(l, 16, 64);
      l += __shfl_xor(l, 32, 64);
      float inv = 1.0f / l;
#pragma unroll
      for (int db = 0; db < 4; ++db) {
        u16x4 o;
#pragma unroll
        for (int r = 0; r < 4; ++r) o[r] = f2bf(oaccT[s][db][r] * inv);
        *(u16x4*)(qh + (size_t)(q0 + s * 16 + l16) * D_MODEL + db * 16 + quad * 4) = o;
      }
    }
  }
}

// ---- final: d_out <- tmp, dtype per detected flag ----
__global__ __launch_bounds__(256) void final_kernel(
    const float* __restrict__ tmp, void* __restrict__ out,
    const int* __restrict__ flag)
{
  const int bf = *flag;
  size_t i = ((size_t)blockIdx.x * 256 + threadIdx.x) * 8;
  f32x4 lo = *(const f32x4*)(tmp + i);
  f32x4 hi = *(const f32x4*)(tmp + i + 4);
  if (bf) {
    bf16x8 r;
    r[0] = (short)f2bf(lo[0]); r[1] = (short)f2bf(lo[1]);
    r[2] = (short)f2bf(lo[2]); r[3] = (short)f2bf(lo[3]);
    r[4] = (short)f2bf(hi[0]); r[5] = (short)f2bf(hi[1]);
    r[6] = (short)f2bf(hi[2]); r[7] = (short)f2bf(hi[3]);
    *(bf16x8*)((unsigned short*)out + i) = r;
  } else {
    *(f32x4*)((float*)out + i) = lo;
    *(f32x4*)((float*)out + i + 4) = hi;
  }
}

extern "C" void kernel_launch(void* const* d_in, const int* in_sizes, int n_in,
                              void* d_out, int out_size, void* d_ws, size_t ws_size,
                              hipStream_t stream) {
  const void* X  = d_in[0];
  const void* Wq = d_in[1];
  const void* Wk = d_in[2];
  const void* Wv = d_in[3];
  const void* Wo = d_in[4];
  const int* causal = (const int*)d_in[5];

  const size_t NE = (size_t)2 * SEQ * D_MODEL;   // 4,194,304 elems
  const size_t WE = (size_t)D_MODEL * D_MODEL;   // 1,048,576 elems
  int* flag0 = (int*)d_ws;
  int* flag1 = flag0 + 1;
  unsigned short* kws = (unsigned short*)((char*)d_ws + 64);  // K  [b,h,s,d]  8MB
  unsigned short* vws = kws + NE;                             // V^T [b,h,d,s] 8MB
  float* tmp = (float*)kws;                                   // 16MB over dead K+V
  unsigned short* Wb = vws + NE;                              // 4x bf16 W, 8MB
  unsigned short* qd = (unsigned short*)d_out;                // Q bf16, lower 8MB
  unsigned short* Xb = qd + NE;                               // X bf16, upper 8MB (f32 out)

  const bool big = ws_size >= (size_t)64 + 24ull * 1024 * 1024;

  hipLaunchKernelGGL(detect_kernel, dim3(1), dim3(64), 0, stream,
                     (const unsigned short*)X, flag0);
  if (big) {
    hipLaunchKernelGGL(convert_kernel, dim3(2048, 5), dim3(256), 0, stream,
                       X, Wq, Wk, Wv, Wo, flag0, Xb, Wb);
    hipLaunchKernelGGL(qkv_fast_kernel, dim3(8, 32, 3), dim3(256), 0, stream,
                       Xb, Wb, qd, kws, vws);
    hipLaunchKernelGGL(attn_kernel, dim3(512), dim3(128), 0, stream,
                       qd, kws, vws, causal);
    hipLaunchKernelGGL(oproj_fast_kernel, dim3(8, 32), dim3(256), 0, stream,
                       qd, Wb + 3 * WE, tmp);
  } else {
    hipLaunchKernelGGL(qkv_kernel, dim3(8, 32, 3), dim3(256), 0, stream,
                       X, Wq, Wk, Wv, flag0, qd, kws, vws);
    hipLaunchKernelGGL(attn_kernel, dim3(512), dim3(128), 0, stream,
                       qd, kws, vws, causal);
    hipLaunchKernelGGL(oproj_kernel, dim3(8, 32), dim3(256), 0, stream,
                       qd, Wo, flag0, tmp);
  }
  hipLaunchKernelGGL(final_kernel, dim3(2048), dim3(256), 0, stream,
                     tmp, d_out, flag0);
}